// Round 3
// baseline (63.521 us; speedup 1.0000x reference)
//
#include <hip/hip_runtime.h>
#include <hip/hip_bf16.h>

// Decoder: preds[s,b] = hidden[s,b,:] @ W[0] + b[0]  (S=4096, B=64, H=256)
// loss = sum((preds - outputs.T)^2); d_out = [loss, preds.reshape(-1)]
//
// Memory-bound: hidden = 256 MiB f32 read once -> HBM floor ~44 us.
// R2: interleaved column ownership. Lane l16 owns float4 cols
// {l16, l16+16, l16+32, l16+48} so EVERY load instruction is 16-lane
// contiguous (256B/segment) instead of stride-64B (R1's mistake).

constexpr int S = 4096;
constexpr int B = 64;
constexpr int H = 256;
constexpr int P = S * B;          // 262144 pred rows
constexpr int BLOCK = 256;        // 4 waves/block
constexpr int GRID = 2048;        // 8192 waves; 4 rows/wave/iter -> 8 iters

__global__ __launch_bounds__(BLOCK) void decoder_kernel(
    const float* __restrict__ outputs,   // [B, S]
    const float* __restrict__ hidden,    // [S, B, H]
    const float* __restrict__ W,         // [1, H]
    const float* __restrict__ bias,      // [1]
    float* __restrict__ out)             // [1 + P]: out[0]=loss, out[1+p]=pred
{
    const int lane = threadIdx.x & 63;
    const int sub  = lane >> 4;          // which of the 4 rows this lane serves
    const int l16  = lane & 15;          // lane within the 16-lane row group
    const int gwave  = (blockIdx.x * BLOCK + threadIdx.x) >> 6;
    const int nwaves = (GRID * BLOCK) >> 6;  // 8192

    // Interleaved W ownership: float4 cols l16 + {0,16,32,48}.
    const float4* W4 = reinterpret_cast<const float4*>(W);
    const float4 w0 = W4[l16];
    const float4 w1 = W4[l16 + 16];
    const float4 w2 = W4[l16 + 32];
    const float4 w3 = W4[l16 + 48];
    const float b0 = bias[0];

    float se_acc = 0.0f;

    for (int base = gwave * 4; base < P; base += nwaves * 4) {
        const int p = base + sub;
        const float4* hp = reinterpret_cast<const float4*>(hidden + (size_t)p * H);
        const float4 h0 = hp[l16];
        const float4 h1 = hp[l16 + 16];
        const float4 h2 = hp[l16 + 32];
        const float4 h3 = hp[l16 + 48];

        float d = h0.x * w0.x + h0.y * w0.y + h0.z * w0.z + h0.w * w0.w;
        d += h1.x * w1.x + h1.y * w1.y + h1.z * w1.z + h1.w * w1.w;
        d += h2.x * w2.x + h2.y * w2.y + h2.z * w2.z + h2.w * w2.w;
        d += h3.x * w3.x + h3.y * w3.y + h3.z * w3.z + h3.w * w3.w;

        // Reduce across the 16-lane group (xor 1,2,4,8 stays within group).
        #pragma unroll
        for (int off = 1; off < 16; off <<= 1)
            d += __shfl_xor(d, off, 64);

        if (l16 == 0) {
            const float pred = d + b0;
            out[1 + p] = pred;
            const int s  = p >> 6;       // p = s*B + bb, B=64
            const int bb = p & 63;
            const float diff = pred - outputs[bb * S + s];
            se_acc += diff * diff;
        }
    }

    // Wave-level reduce of se_acc (non-leader lanes hold 0), then one
    // atomic per block.
    #pragma unroll
    for (int off = 32; off > 0; off >>= 1)
        se_acc += __shfl_xor(se_acc, off, 64);

    __shared__ float lsum[BLOCK / 64];
    if (lane == 0) lsum[threadIdx.x >> 6] = se_acc;
    __syncthreads();
    if (threadIdx.x == 0) {
        atomicAdd(out, lsum[0] + lsum[1] + lsum[2] + lsum[3]);
    }
}

extern "C" void kernel_launch(void* const* d_in, const int* in_sizes, int n_in,
                              void* d_out, int out_size, void* d_ws, size_t ws_size,
                              hipStream_t stream) {
    const float* outputs = (const float*)d_in[0];  // [B, S]
    const float* hidden  = (const float*)d_in[1];  // [S, B, H]
    const float* W       = (const float*)d_in[2];  // [1, H]
    const float* bias    = (const float*)d_in[3];  // [1]
    float* out = (float*)d_out;                    // [1 + S*B]

    // Atomic accumulator must start at 0 every call (harness doesn't re-poison).
    hipMemsetAsync(out, 0, sizeof(float), stream);

    decoder_kernel<<<GRID, BLOCK, 0, stream>>>(outputs, hidden, W, bias, out);
}

// Round 4
// 52.698 us; speedup vs baseline: 1.2054x; 1.2054x over previous
//
#include <hip/hip_runtime.h>
#include <hip/hip_bf16.h>

// Decoder: preds[s,b] = hidden[s,b,:] @ W[0] + b[0]  (S=4096, B=64, H=256)
// loss = sum((preds - outputs.T)^2); d_out = [loss, preds.reshape(-1)]
//
// Memory-bound: hidden = 256 MiB f32 read once -> HBM floor ~41-44 us.
// R3: (a) no memset / no atomics -- per-block partials to d_ws + tiny
//     reduce kernel (removes a serialized graph node);
//     (b) wave owns 32 consecutive rows: preds gathered to lanes via one
//     broadcast shuffle per iteration, then ONE coalesced 128B store and
//     ONE outputs read per wave (hot loop has zero scattered accesses);
//     (c) R1 blocked load layout kept (R2 interleave regressed).

constexpr int S = 4096;
constexpr int B = 64;
constexpr int H = 256;
constexpr int P = S * B;            // 262144 rows
constexpr int BLOCK = 256;          // 4 waves/block
constexpr int GRID = 2048;          // 8192 waves * 32 rows/wave = P exactly
constexpr int NBLK = GRID;

__global__ __launch_bounds__(BLOCK, 4) void decoder_main(
    const float* __restrict__ outputs,   // [B, S]
    const float* __restrict__ hidden,    // [S, B, H]
    const float* __restrict__ W,         // [1, H]
    const float* __restrict__ bias,      // [1]
    float* __restrict__ out,             // [1 + P]; we write out[1..P]
    float* __restrict__ ws)              // [NBLK] per-block loss partials
{
    const int tid  = threadIdx.x;
    const int lane = tid & 63;
    const int sub  = lane >> 4;          // row subgroup (0..3)
    const int l16  = lane & 15;          // lane within 16-lane row group
    const int gwave = (blockIdx.x * BLOCK + tid) >> 6;   // 0..8191
    const int base  = gwave * 32;        // this wave's 32 consecutive rows

    // Blocked W ownership (R1 layout): lane owns cols [l16*16, l16*16+16).
    const float4* W4 = reinterpret_cast<const float4*>(W) + l16 * 4;
    const float4 w0 = W4[0], w1 = W4[1], w2 = W4[2], w3 = W4[3];
    const float b0 = bias[0];

    // Lane L (<32) will end holding the dot for row base+L:
    // produced at iteration t = L>>2 by subgroup L&3.
    const int tsel = lane >> 2;
    const int gsel = (lane & 3) << 4;    // a lane inside subgroup (L&3)

    float my_dot = 0.0f;

    #pragma unroll
    for (int t = 0; t < 8; ++t) {
        const int p = base + 4 * t + sub;
        const float4* hp =
            reinterpret_cast<const float4*>(hidden + (size_t)p * H) + l16 * 4;
        const float4 h0 = hp[0], h1 = hp[1], h2 = hp[2], h3 = hp[3];

        float d = h0.x * w0.x + h0.y * w0.y + h0.z * w0.z + h0.w * w0.w;
        d += h1.x * w1.x + h1.y * w1.y + h1.z * w1.z + h1.w * w1.w;
        d += h2.x * w2.x + h2.y * w2.y + h2.z * w2.z + h2.w * w2.w;
        d += h3.x * w3.x + h3.y * w3.y + h3.z * w3.z + h3.w * w3.w;

        // Reduce within each 16-lane group (row dot, broadcast to group).
        #pragma unroll
        for (int off = 1; off < 16; off <<= 1)
            d += __shfl_xor(d, off, 64);

        // Gather: lane L grabs subgroup (L&3)'s dot; keeps it if t == L>>2.
        const float g = __shfl(d, gsel, 64);
        if (t == tsel) my_dot = g;
    }

    // Epilogue: coalesced pred store + loss contribution (lanes 0..31).
    float se = 0.0f;
    if (lane < 32) {
        const float pred = my_dot + b0;
        out[1 + base + lane] = pred;               // 128B contiguous store
        const int s_idx = base >> 6;               // same s for all 32 rows
        const int bb    = (base & 63) + lane;      // bb in [0,64)
        const float diff = pred - outputs[bb * S + s_idx];
        se = diff * diff;
    }

    // Wave then block reduce of squared-error partials; one store per block.
    #pragma unroll
    for (int off = 32; off > 0; off >>= 1)
        se += __shfl_xor(se, off, 64);

    __shared__ float lsum[BLOCK / 64];
    if (lane == 0) lsum[tid >> 6] = se;
    __syncthreads();
    if (tid == 0) ws[blockIdx.x] = lsum[0] + lsum[1] + lsum[2] + lsum[3];
}

__global__ __launch_bounds__(BLOCK) void decoder_loss(
    const float* __restrict__ ws,        // [NBLK]
    float* __restrict__ out)             // out[0] = loss
{
    const int tid = threadIdx.x;
    float s = 0.0f;
    #pragma unroll
    for (int i = 0; i < NBLK / BLOCK; ++i)   // 8 coalesced passes
        s += ws[tid + BLOCK * i];
    #pragma unroll
    for (int off = 32; off > 0; off >>= 1)
        s += __shfl_xor(s, off, 64);
    __shared__ float lsum[BLOCK / 64];
    if ((tid & 63) == 0) lsum[tid >> 6] = s;
    __syncthreads();
    if (tid == 0) out[0] = lsum[0] + lsum[1] + lsum[2] + lsum[3];
}

extern "C" void kernel_launch(void* const* d_in, const int* in_sizes, int n_in,
                              void* d_out, int out_size, void* d_ws, size_t ws_size,
                              hipStream_t stream) {
    const float* outputs = (const float*)d_in[0];  // [B, S]
    const float* hidden  = (const float*)d_in[1];  // [S, B, H]
    const float* W       = (const float*)d_in[2];  // [1, H]
    const float* bias    = (const float*)d_in[3];  // [1]
    float* out = (float*)d_out;                    // [1 + S*B]
    float* ws  = (float*)d_ws;                     // >= NBLK floats

    decoder_main<<<GRID, BLOCK, 0, stream>>>(outputs, hidden, W, bias, out, ws);
    decoder_loss<<<1, BLOCK, 0, stream>>>(ws, out);
}